// Round 4
// baseline (388.935 us; speedup 1.0000x reference)
//
#include <hip/hip_runtime.h>
#include <hip/hip_bf16.h>

typedef short bhalf8 __attribute__((ext_vector_type(8)));   // 8 x bf16 = 4 VGPRs
typedef float floatx4 __attribute__((ext_vector_type(4)));  // MFMA C/D frag

#define D_MODEL 1024
#define SEQ     2048
#define BATCH   2
#define NHEAD   16
#define DH      64

static __device__ __forceinline__ short f2bf(float f) {
    unsigned u = __builtin_bit_cast(unsigned, f);
    u = (u + 0x7fffu + ((u >> 16) & 1u)) >> 16;   // RNE fp32 -> bf16
    return (short)u;
}
static __device__ __forceinline__ unsigned pack2(float a, float b) {
    return (unsigned)(unsigned short)f2bf(a) | ((unsigned)(unsigned short)f2bf(b) << 16);
}

// Stage 16 K-contiguous elements of one row into LDS as bf16 shorts.
template <bool F32>
static __device__ __forceinline__ void stage16(const void* __restrict__ src,
                                               size_t off, short* dst) {
    if constexpr (F32) {
        const float* f = (const float*)src + off;
        float4 a = *(const float4*)(f);
        float4 b = *(const float4*)(f + 4);
        float4 c = *(const float4*)(f + 8);
        float4 d = *(const float4*)(f + 12);
        uint4 lo = {pack2(a.x, a.y), pack2(a.z, a.w), pack2(b.x, b.y), pack2(b.z, b.w)};
        uint4 hi = {pack2(c.x, c.y), pack2(c.z, c.w), pack2(d.x, d.y), pack2(d.z, d.w)};
        *(uint4*)dst       = lo;
        *(uint4*)(dst + 8) = hi;
    } else {
        const short* s = (const short*)src + off;
        *(uint4*)dst       = *(const uint4*)s;
        *(uint4*)(dst + 8) = *(const uint4*)(s + 8);
    }
}

// ---------------------------------------------------------------------------
// GEMM: C[m][n] = sum_k A[m][k] * W[n][k]  (C = A*W^T).
// A: MxK row-major (fp32 or bf16), W: NxK row-major (fp32 or bf16).
// OUTF32: C is float* (fp32 store), else bf16 short*.
// 64x64 tile/block, 4 waves each a 32x32 quadrant, BK=64, 16x16x32 bf16 MFMA.
// ---------------------------------------------------------------------------
template <bool AF32, bool WF32, bool OUTF32>
__global__ __launch_bounds__(256) void gemm_bt(const void* __restrict__ A,
                                               const void* __restrict__ W,
                                               void* __restrict__ C,
                                               int M, int N, int K) {
    __shared__ short As[64][72];
    __shared__ short Ws[64][72];
    const int t    = threadIdx.x;
    const int wave = t >> 6, lane = t & 63, quad = lane >> 4, l16 = lane & 15;
    const int bm = blockIdx.x * 64, bn = blockIdx.y * 64;
    const int r  = t >> 2, cg = (t & 3) * 16;
    const int qm = (wave >> 1) * 32, qn = (wave & 1) * 32;

    floatx4 acc[2][2];
#pragma unroll
    for (int i = 0; i < 2; ++i)
#pragma unroll
        for (int j = 0; j < 2; ++j) {
            floatx4 z = {0.f, 0.f, 0.f, 0.f};
            acc[i][j] = z;
        }

    for (int k0 = 0; k0 < K; k0 += 64) {
        stage16<AF32>(A, (size_t)(bm + r) * K + cg + k0, &As[r][cg]);
        stage16<WF32>(W, (size_t)(bn + r) * K + cg + k0, &Ws[r][cg]);
        __syncthreads();
#pragma unroll
        for (int kk = 0; kk < 64; kk += 32) {
            bhalf8 a0f = *(const bhalf8*)&As[qm + l16][kk + quad * 8];
            bhalf8 a1f = *(const bhalf8*)&As[qm + 16 + l16][kk + quad * 8];
            bhalf8 b0f = *(const bhalf8*)&Ws[qn + l16][kk + quad * 8];
            bhalf8 b1f = *(const bhalf8*)&Ws[qn + 16 + l16][kk + quad * 8];
            acc[0][0] = __builtin_amdgcn_mfma_f32_16x16x32_bf16(a0f, b0f, acc[0][0], 0, 0, 0);
            acc[0][1] = __builtin_amdgcn_mfma_f32_16x16x32_bf16(a0f, b1f, acc[0][1], 0, 0, 0);
            acc[1][0] = __builtin_amdgcn_mfma_f32_16x16x32_bf16(a1f, b0f, acc[1][0], 0, 0, 0);
            acc[1][1] = __builtin_amdgcn_mfma_f32_16x16x32_bf16(a1f, b1f, acc[1][1], 0, 0, 0);
        }
        __syncthreads();
    }

    // C/D layout (m89-verified): col = lane&15, row = quad*4 + reg
#pragma unroll
    for (int i = 0; i < 2; ++i)
#pragma unroll
        for (int j = 0; j < 2; ++j)
#pragma unroll
            for (int g = 0; g < 4; ++g) {
                int row = bm + qm + i * 16 + quad * 4 + g;
                int col = bn + qn + j * 16 + l16;
                if constexpr (OUTF32)
                    ((float*)C)[(size_t)row * N + col] = acc[i][j][g];
                else
                    ((short*)C)[(size_t)row * N + col] = f2bf(acc[i][j][g]);
            }
}

// ---------------------------------------------------------------------------
// Causal flash attention. Q,K,V,Y all [B*S, D_MODEL] bf16; head h occupies
// columns h*64..h*64+63. One wave per 16-row Q tile; K-chunks of 32 with
// online softmax; P routed C-layout -> A-layout via per-wave LDS (m120).
// Validated r2==r3: computes same function as naive fp32 attention.
// ---------------------------------------------------------------------------
__global__ __launch_bounds__(256) void attn_kernel(const short* __restrict__ Q,
                                                   const short* __restrict__ K,
                                                   const short* __restrict__ V,
                                                   short* __restrict__ Y) {
    __shared__ __align__(16) short p_lds[4][16 * 32];
    const int t    = threadIdx.x;
    const int wave = t >> 6, lane = t & 63, quad = lane >> 4, l16 = lane & 15;
    const int bh = blockIdx.y;            // b*NHEAD + h
    const int b = bh >> 4, h = bh & 15;
    const int qb = blockIdx.x * 64 + wave * 16;

    const size_t hb = (size_t)b * SEQ * D_MODEL + (size_t)h * DH;
    const short* Qb = Q + hb;
    const short* Kb = K + hb;
    const short* Vb = V + hb;

    bhalf8 qf0 = *(const bhalf8*)(Qb + (size_t)(qb + l16) * D_MODEL + quad * 8);
    bhalf8 qf1 = *(const bhalf8*)(Qb + (size_t)(qb + l16) * D_MODEL + 32 + quad * 8);

    float m_i[4], l_i[4];
    floatx4 o[4];
#pragma unroll
    for (int g = 0; g < 4; ++g) { m_i[g] = -1e30f; l_i[g] = 0.f; }
#pragma unroll
    for (int nd = 0; nd < 4; ++nd) {
        floatx4 z = {0.f, 0.f, 0.f, 0.f};
        o[nd] = z;
    }
    const float scale = 0.125f;  // 1/sqrt(64)

    for (int k0 = 0; k0 < qb + 16; k0 += 32) {
        floatx4 s[2];
#pragma unroll
        for (int t2 = 0; t2 < 2; ++t2) {
            const short* kr = Kb + (size_t)(k0 + t2 * 16 + l16) * D_MODEL;
            bhalf8 kf0 = *(const bhalf8*)(kr + quad * 8);
            bhalf8 kf1 = *(const bhalf8*)(kr + 32 + quad * 8);
            floatx4 z = {0.f, 0.f, 0.f, 0.f};
            z = __builtin_amdgcn_mfma_f32_16x16x32_bf16(qf0, kf0, z, 0, 0, 0);
            z = __builtin_amdgcn_mfma_f32_16x16x32_bf16(qf1, kf1, z, 0, 0, 0);
            s[t2] = z;
        }

#pragma unroll
        for (int g = 0; g < 4; ++g) {
            int qrow = qb + quad * 4 + g;
            float s0 = s[0][g] * scale;
            float s1 = s[1][g] * scale;
            if (k0 + l16 > qrow) s0 = -1e9f;
            if (k0 + 16 + l16 > qrow) s1 = -1e9f;
            float mx = fmaxf(s0, s1);
#pragma unroll
            for (int off = 1; off < 16; off <<= 1) mx = fmaxf(mx, __shfl_xor(mx, off, 64));
            float mn = fmaxf(m_i[g], mx);
            float p0 = __expf(s0 - mn);
            float p1 = __expf(s1 - mn);
            float alpha = __expf(m_i[g] - mn);
            m_i[g] = mn;
            float rs = p0 + p1;
#pragma unroll
            for (int off = 1; off < 16; off <<= 1) rs += __shfl_xor(rs, off, 64);
            l_i[g] = l_i[g] * alpha + rs;
#pragma unroll
            for (int nd = 0; nd < 4; ++nd) o[nd][g] *= alpha;
            int rr = quad * 4 + g;
            p_lds[wave][rr * 32 + l16]      = f2bf(p0);
            p_lds[wave][rr * 32 + 16 + l16] = f2bf(p1);
        }

        bhalf8 ap = *(const bhalf8*)&p_lds[wave][l16 * 32 + quad * 8];

#pragma unroll
        for (int nd = 0; nd < 4; ++nd) {
            bhalf8 vf;
#pragma unroll
            for (int jj = 0; jj < 8; ++jj)
                vf[jj] = Vb[(size_t)(k0 + quad * 8 + jj) * D_MODEL + nd * 16 + l16];
            o[nd] = __builtin_amdgcn_mfma_f32_16x16x32_bf16(ap, vf, o[nd], 0, 0, 0);
        }
    }

#pragma unroll
    for (int nd = 0; nd < 4; ++nd)
#pragma unroll
        for (int g = 0; g < 4; ++g) {
            int qrow = qb + quad * 4 + g;
            float val = o[nd][g] / l_i[g];
            Y[(size_t)(b * SEQ + qrow) * D_MODEL + h * DH + nd * 16 + l16] = f2bf(val);
        }
}

// ---------------------------------------------------------------------------
extern "C" void kernel_launch(void* const* d_in, const int* in_sizes, int n_in,
                              void* d_out, int out_size, void* d_ws, size_t ws_size,
                              hipStream_t stream) {
    // I/O axioms (evidence): inputs fp32 (r1: bf16 reads -> NaN from fp32 bit
    // patterns). OUTPUT fp32 per template rule "reference output dtype else
    // float*" — r2/r3 wrote bf16 and got identical 4.25 errors with two
    // different attention kernels, i.e. compute was consistent and the output
    // format was the shared bug. The "(bf16)" test label is the comparison
    // mode (bf16-rounded compare, 8-ulp floor), not the buffer dtype.
    const void* x  = d_in[0];
    const void* wq = d_in[1];
    const void* wk = d_in[2];
    const void* wv = d_in[3];
    const void* wo = d_in[4];

    const int M = BATCH * SEQ;                  // 4096
    const size_t sz = (size_t)M * D_MODEL;
    short* Qw = (short*)d_ws;
    short* Kw = Qw + sz;
    short* Vw = Kw + sz;
    short* Yw = Vw + sz;                        // 33.5 MB of ws

    dim3 gg(M / 64, D_MODEL / 64);
    gemm_bt<true, true, false><<<gg, 256, 0, stream>>>(x, wq, Qw, M, D_MODEL, D_MODEL);
    gemm_bt<true, true, false><<<gg, 256, 0, stream>>>(x, wk, Kw, M, D_MODEL, D_MODEL);
    gemm_bt<true, true, false><<<gg, 256, 0, stream>>>(x, wv, Vw, M, D_MODEL, D_MODEL);
    attn_kernel<<<dim3(SEQ / 64, BATCH * NHEAD), 256, 0, stream>>>(Qw, Kw, Vw, Yw);
    gemm_bt<false, true, true><<<gg, 256, 0, stream>>>(Yw, wo, d_out, M, D_MODEL, D_MODEL);
}

// Round 5
// 323.537 us; speedup vs baseline: 1.2021x; 1.2021x over previous
//
#include <hip/hip_runtime.h>

typedef short bhalf8 __attribute__((ext_vector_type(8)));   // 8 x bf16 = 4 VGPRs
typedef float floatx4 __attribute__((ext_vector_type(4)));  // MFMA C/D frag

#define D_MODEL 1024
#define SEQ     2048
#define BATCH   2
#define NHEAD   16
#define DH      64

static __device__ __forceinline__ short f2bf(float f) {
    unsigned u = __builtin_bit_cast(unsigned, f);
    u = (u + 0x7fffu + ((u >> 16) & 1u)) >> 16;   // RNE fp32 -> bf16
    return (short)u;
}
static __device__ __forceinline__ unsigned pack2(float a, float b) {
    return (unsigned)(unsigned short)f2bf(a) | ((unsigned)(unsigned short)f2bf(b) << 16);
}

// ---------------------------------------------------------------------------
// Elementwise fp32 -> bf16 cast, 8 elems/thread, exact grid.
// ---------------------------------------------------------------------------
__global__ __launch_bounds__(256) void cast_bf16(const float* __restrict__ s,
                                                 short* __restrict__ d, int n) {
    int i = (blockIdx.x * 256 + threadIdx.x) * 8;
    if (i + 7 >= n) return;
    float4 a = *(const float4*)(s + i);
    float4 b = *(const float4*)(s + i + 4);
    uint4 u = {pack2(a.x, a.y), pack2(a.z, a.w), pack2(b.x, b.y), pack2(b.z, b.w)};
    *(uint4*)(d + i) = u;
}

// ---------------------------------------------------------------------------
// Fast GEMM: C = A * W^T, A MxK bf16, W NxK bf16. 128x128 tile, BK=64,
// 4 waves each 64x64 (4x4 of 16x16x32 MFMA). LDS padded 64->72.
// ---------------------------------------------------------------------------
template <bool OUTF32>
__global__ __launch_bounds__(256) void gemm128_bt(const short* __restrict__ A,
                                                  const short* __restrict__ W,
                                                  void* __restrict__ C,
                                                  int M, int N, int K) {
    __shared__ short As[128][72];
    __shared__ short Bs[128][72];
    const int t    = threadIdx.x;
    const int wave = t >> 6, lane = t & 63, quad = lane >> 4, l16 = lane & 15;
    const int bm = blockIdx.x * 128, bn = blockIdx.y * 128;
    const int qm = (wave >> 1) * 64, qn = (wave & 1) * 64;
    const int srow = t >> 1, shalf = (t & 1) * 32;   // staging: row, 32-col half

    const short* Ap = A + (size_t)(bm + srow) * K + shalf;
    const short* Wp = W + (size_t)(bn + srow) * K + shalf;

    floatx4 acc[4][4];
#pragma unroll
    for (int i = 0; i < 4; ++i)
#pragma unroll
        for (int j = 0; j < 4; ++j) {
            floatx4 z = {0.f, 0.f, 0.f, 0.f};
            acc[i][j] = z;
        }

    for (int k0 = 0; k0 < K; k0 += 64) {
        uint4 la[4], lb[4];
#pragma unroll
        for (int j = 0; j < 4; ++j) {
            la[j] = *(const uint4*)(Ap + k0 + j * 8);
            lb[j] = *(const uint4*)(Wp + k0 + j * 8);
        }
#pragma unroll
        for (int j = 0; j < 4; ++j) {
            *(uint4*)&As[srow][shalf + j * 8] = la[j];
            *(uint4*)&Bs[srow][shalf + j * 8] = lb[j];
        }
        __syncthreads();
#pragma unroll
        for (int kk = 0; kk < 64; kk += 32) {
            bhalf8 af[4], bf[4];
#pragma unroll
            for (int im = 0; im < 4; ++im)
                af[im] = *(const bhalf8*)&As[qm + im * 16 + l16][kk + quad * 8];
#pragma unroll
            for (int jn = 0; jn < 4; ++jn)
                bf[jn] = *(const bhalf8*)&Bs[qn + jn * 16 + l16][kk + quad * 8];
#pragma unroll
            for (int im = 0; im < 4; ++im)
#pragma unroll
                for (int jn = 0; jn < 4; ++jn)
                    acc[im][jn] = __builtin_amdgcn_mfma_f32_16x16x32_bf16(
                        af[im], bf[jn], acc[im][jn], 0, 0, 0);
        }
        __syncthreads();
    }

    // C/D layout (m89): col = lane&15, row = quad*4 + reg
#pragma unroll
    for (int im = 0; im < 4; ++im)
#pragma unroll
        for (int jn = 0; jn < 4; ++jn)
#pragma unroll
            for (int g = 0; g < 4; ++g) {
                int row = bm + qm + im * 16 + quad * 4 + g;
                int col = bn + qn + jn * 16 + l16;
                if constexpr (OUTF32)
                    ((float*)C)[(size_t)row * N + col] = acc[im][jn][g];
                else
                    ((short*)C)[(size_t)row * N + col] = f2bf(acc[im][jn][g]);
            }
}

// ---------------------------------------------------------------------------
// Fallback GEMM (r4): fp32/bf16 operands staged+converted in registers, 64x64.
// Used only if ws_size can't hold the bf16 pre-cast copies.
// ---------------------------------------------------------------------------
template <bool F32>
static __device__ __forceinline__ void stage16(const void* __restrict__ src,
                                               size_t off, short* dst) {
    if constexpr (F32) {
        const float* f = (const float*)src + off;
        float4 a = *(const float4*)(f);
        float4 b = *(const float4*)(f + 4);
        float4 c = *(const float4*)(f + 8);
        float4 d = *(const float4*)(f + 12);
        uint4 lo = {pack2(a.x, a.y), pack2(a.z, a.w), pack2(b.x, b.y), pack2(b.z, b.w)};
        uint4 hi = {pack2(c.x, c.y), pack2(c.z, c.w), pack2(d.x, d.y), pack2(d.z, d.w)};
        *(uint4*)dst       = lo;
        *(uint4*)(dst + 8) = hi;
    } else {
        const short* s = (const short*)src + off;
        *(uint4*)dst       = *(const uint4*)s;
        *(uint4*)(dst + 8) = *(const uint4*)(s + 8);
    }
}

template <bool AF32, bool WF32, bool OUTF32>
__global__ __launch_bounds__(256) void gemm_bt(const void* __restrict__ A,
                                               const void* __restrict__ W,
                                               void* __restrict__ C,
                                               int M, int N, int K) {
    __shared__ short As[64][72];
    __shared__ short Ws[64][72];
    const int t    = threadIdx.x;
    const int wave = t >> 6, lane = t & 63, quad = lane >> 4, l16 = lane & 15;
    const int bm = blockIdx.x * 64, bn = blockIdx.y * 64;
    const int r  = t >> 2, cg = (t & 3) * 16;
    const int qm = (wave >> 1) * 32, qn = (wave & 1) * 32;

    floatx4 acc[2][2];
#pragma unroll
    for (int i = 0; i < 2; ++i)
#pragma unroll
        for (int j = 0; j < 2; ++j) {
            floatx4 z = {0.f, 0.f, 0.f, 0.f};
            acc[i][j] = z;
        }

    for (int k0 = 0; k0 < K; k0 += 64) {
        stage16<AF32>(A, (size_t)(bm + r) * K + cg + k0, &As[r][cg]);
        stage16<WF32>(W, (size_t)(bn + r) * K + cg + k0, &Ws[r][cg]);
        __syncthreads();
#pragma unroll
        for (int kk = 0; kk < 64; kk += 32) {
            bhalf8 a0f = *(const bhalf8*)&As[qm + l16][kk + quad * 8];
            bhalf8 a1f = *(const bhalf8*)&As[qm + 16 + l16][kk + quad * 8];
            bhalf8 b0f = *(const bhalf8*)&Ws[qn + l16][kk + quad * 8];
            bhalf8 b1f = *(const bhalf8*)&Ws[qn + 16 + l16][kk + quad * 8];
            acc[0][0] = __builtin_amdgcn_mfma_f32_16x16x32_bf16(a0f, b0f, acc[0][0], 0, 0, 0);
            acc[0][1] = __builtin_amdgcn_mfma_f32_16x16x32_bf16(a0f, b1f, acc[0][1], 0, 0, 0);
            acc[1][0] = __builtin_amdgcn_mfma_f32_16x16x32_bf16(a1f, b0f, acc[1][0], 0, 0, 0);
            acc[1][1] = __builtin_amdgcn_mfma_f32_16x16x32_bf16(a1f, b1f, acc[1][1], 0, 0, 0);
        }
        __syncthreads();
    }

#pragma unroll
    for (int i = 0; i < 2; ++i)
#pragma unroll
        for (int j = 0; j < 2; ++j)
#pragma unroll
            for (int g = 0; g < 4; ++g) {
                int row = bm + qm + i * 16 + quad * 4 + g;
                int col = bn + qn + j * 16 + l16;
                if constexpr (OUTF32)
                    ((float*)C)[(size_t)row * N + col] = acc[i][j][g];
                else
                    ((short*)C)[(size_t)row * N + col] = f2bf(acc[i][j][g]);
            }
}

// ---------------------------------------------------------------------------
// Flash attention v2 — block-cooperative. Block = 128 Q-rows of one (b,h);
// 4 waves x 32 rows. K-chunks of 64 staged in LDS (V transposed on store).
// Q,K,V,Y: [B*S, D_MODEL] bf16, head h at cols h*64..h*64+63.
// ---------------------------------------------------------------------------
__global__ __launch_bounds__(256) void attn_v2(const short* __restrict__ Q,
                                               const short* __restrict__ K,
                                               const short* __restrict__ V,
                                               short* __restrict__ Y) {
    __shared__ short Ks[64][72];        // [kcol][d]
    __shared__ short Vt[64][72];        // [d][kcol] (transposed)
    __shared__ short Ps[4][32][72];     // per-wave P, [qrow][kcol]
    const int t    = threadIdx.x;
    const int wave = t >> 6, lane = t & 63, quad = lane >> 4, l16 = lane & 15;
    const int bh = blockIdx.y, b = bh >> 4, h = bh & 15;
    const int qb = blockIdx.x * 128;
    const int qw = qb + wave * 32;      // this wave's first Q row

    const size_t hb = (size_t)b * SEQ * D_MODEL + (size_t)h * DH;
    const short* Qb = Q + hb;
    const short* Kb = K + hb;
    const short* Vb = V + hb;

    // persistent Q A-frags: 2 row-tiles x 2 d-halves
    bhalf8 qf[2][2];
#pragma unroll
    for (int im = 0; im < 2; ++im) {
        const short* qr = Qb + (size_t)(qw + im * 16 + l16) * D_MODEL;
        qf[im][0] = *(const bhalf8*)(qr + quad * 8);
        qf[im][1] = *(const bhalf8*)(qr + 32 + quad * 8);
    }

    float m_i[2][4], l_i[2][4];
    floatx4 o[2][4];
#pragma unroll
    for (int im = 0; im < 2; ++im)
#pragma unroll
        for (int g = 0; g < 4; ++g) { m_i[im][g] = -1e30f; l_i[im][g] = 0.f; }
#pragma unroll
    for (int im = 0; im < 2; ++im)
#pragma unroll
        for (int nd = 0; nd < 4; ++nd) {
            floatx4 z = {0.f, 0.f, 0.f, 0.f};
            o[im][nd] = z;
        }
    const float scale = 0.125f;         // 1/sqrt(64)

    const int krow = t >> 3, kch = (t & 7) * 8;       // K staging: 32 rows/pass
    const int vkp = (t >> 3) * 2, vd0 = (t & 7) * 8;  // V: 2 k-rows, 8 d each

    for (int k0 = 0; k0 < qb + 128; k0 += 64) {
        // ---- stage K (2 passes) and V (transposed) ----
        uint4 kv0 = *(const uint4*)(Kb + (size_t)(k0 + krow) * D_MODEL + kch);
        uint4 kv1 = *(const uint4*)(Kb + (size_t)(k0 + 32 + krow) * D_MODEL + kch);
        uint4 vv0 = *(const uint4*)(Vb + (size_t)(k0 + vkp) * D_MODEL + vd0);
        uint4 vv1 = *(const uint4*)(Vb + (size_t)(k0 + vkp + 1) * D_MODEL + vd0);
        *(uint4*)&Ks[krow][kch]      = kv0;
        *(uint4*)&Ks[krow + 32][kch] = kv1;
        const unsigned short* p0 = (const unsigned short*)&vv0;
        const unsigned short* p1 = (const unsigned short*)&vv1;
#pragma unroll
        for (int i = 0; i < 8; ++i) {
            unsigned pr = (unsigned)p0[i] | ((unsigned)p1[i] << 16);
            *(unsigned*)&Vt[vd0 + i][vkp] = pr;     // Vt[d][k], k even
        }
        __syncthreads();

        if (k0 < qw + 32) {             // causal: this wave needs this chunk
            // ---- S = Q K^T (32 rows x 64 cols) ----
            bhalf8 kf[4][2];
#pragma unroll
            for (int jn = 0; jn < 4; ++jn) {
                kf[jn][0] = *(const bhalf8*)&Ks[jn * 16 + l16][quad * 8];
                kf[jn][1] = *(const bhalf8*)&Ks[jn * 16 + l16][quad * 8 + 32];
            }
            floatx4 s[2][4];
#pragma unroll
            for (int im = 0; im < 2; ++im)
#pragma unroll
                for (int jn = 0; jn < 4; ++jn) {
                    floatx4 z = {0.f, 0.f, 0.f, 0.f};
                    z = __builtin_amdgcn_mfma_f32_16x16x32_bf16(qf[im][0], kf[jn][0], z, 0, 0, 0);
                    z = __builtin_amdgcn_mfma_f32_16x16x32_bf16(qf[im][1], kf[jn][1], z, 0, 0, 0);
                    s[im][jn] = z;
                }

            // ---- online softmax per row; P -> LDS (A-layout region) ----
#pragma unroll
            for (int im = 0; im < 2; ++im)
#pragma unroll
                for (int g = 0; g < 4; ++g) {
                    const int qrow = qw + im * 16 + quad * 4 + g;
                    float v0 = s[im][0][g] * scale;
                    float v1 = s[im][1][g] * scale;
                    float v2 = s[im][2][g] * scale;
                    float v3 = s[im][3][g] * scale;
                    if (k0 + l16 > qrow)      v0 = -1e9f;
                    if (k0 + 16 + l16 > qrow) v1 = -1e9f;
                    if (k0 + 32 + l16 > qrow) v2 = -1e9f;
                    if (k0 + 48 + l16 > qrow) v3 = -1e9f;
                    float mx = fmaxf(fmaxf(v0, v1), fmaxf(v2, v3));
#pragma unroll
                    for (int off = 1; off < 16; off <<= 1)
                        mx = fmaxf(mx, __shfl_xor(mx, off, 64));
                    const float mn = fmaxf(m_i[im][g], mx);
                    const float alpha = __expf(m_i[im][g] - mn);
                    m_i[im][g] = mn;
                    float p0 = __expf(v0 - mn), p1 = __expf(v1 - mn);
                    float p2 = __expf(v2 - mn), p3 = __expf(v3 - mn);
                    float rs = (p0 + p1) + (p2 + p3);
#pragma unroll
                    for (int off = 1; off < 16; off <<= 1)
                        rs += __shfl_xor(rs, off, 64);
                    l_i[im][g] = l_i[im][g] * alpha + rs;
#pragma unroll
                    for (int nd = 0; nd < 4; ++nd) o[im][nd][g] *= alpha;
                    const int rr = im * 16 + quad * 4 + g;
                    Ps[wave][rr][l16]      = f2bf(p0);
                    Ps[wave][rr][16 + l16] = f2bf(p1);
                    Ps[wave][rr][32 + l16] = f2bf(p2);
                    Ps[wave][rr][48 + l16] = f2bf(p3);
                }

            // ---- O += P V ----
            bhalf8 vt[4][2];
#pragma unroll
            for (int nd = 0; nd < 4; ++nd) {
                vt[nd][0] = *(const bhalf8*)&Vt[nd * 16 + l16][quad * 8];
                vt[nd][1] = *(const bhalf8*)&Vt[nd * 16 + l16][quad * 8 + 32];
            }
#pragma unroll
            for (int im = 0; im < 2; ++im) {
                bhalf8 ap0 = *(const bhalf8*)&Ps[wave][im * 16 + l16][quad * 8];
                bhalf8 ap1 = *(const bhalf8*)&Ps[wave][im * 16 + l16][quad * 8 + 32];
#pragma unroll
                for (int nd = 0; nd < 4; ++nd) {
                    o[im][nd] = __builtin_amdgcn_mfma_f32_16x16x32_bf16(ap0, vt[nd][0], o[im][nd], 0, 0, 0);
                    o[im][nd] = __builtin_amdgcn_mfma_f32_16x16x32_bf16(ap1, vt[nd][1], o[im][nd], 0, 0, 0);
                }
            }
        }
        __syncthreads();
    }

    // ---- epilogue ----
#pragma unroll
    for (int im = 0; im < 2; ++im)
#pragma unroll
        for (int nd = 0; nd < 4; ++nd)
#pragma unroll
            for (int g = 0; g < 4; ++g) {
                const int qrow = qw + im * 16 + quad * 4 + g;
                const float val = o[im][nd][g] / l_i[im][g];
                Y[(size_t)(b * SEQ + qrow) * D_MODEL + h * DH + nd * 16 + l16] = f2bf(val);
            }
}

// ---------------------------------------------------------------------------
extern "C" void kernel_launch(void* const* d_in, const int* in_sizes, int n_in,
                              void* d_out, int out_size, void* d_ws, size_t ws_size,
                              hipStream_t stream) {
    const float* x  = (const float*)d_in[0];
    const float* wq = (const float*)d_in[1];
    const float* wk = (const float*)d_in[2];
    const float* wv = (const float*)d_in[3];
    const float* wo = (const float*)d_in[4];

    const int M = BATCH * SEQ;                    // 4096
    const size_t sz = (size_t)M * D_MODEL;        // 4M elems
    const size_t wsz = (size_t)D_MODEL * D_MODEL; // 1M elems
    short* Qw = (short*)d_ws;
    short* Kw = Qw + sz;
    short* Vw = Kw + sz;
    short* Yw = Vw + sz;                          // 33.5 MB

    const size_t need = (4 * sz + sz + 4 * wsz) * sizeof(short);  // 50.3 MB

    if (ws_size >= need) {
        // fast path: pre-cast everything to bf16, 128x128 MFMA GEMMs
        short* xb  = Yw + sz;
        short* wqb = xb + sz;
        short* wkb = wqb + wsz;
        short* wvb = wkb + wsz;
        short* wob = wvb + wsz;
        cast_bf16<<<(int)(sz / 2048), 256, 0, stream>>>(x, xb, (int)sz);
        cast_bf16<<<(int)(wsz / 2048), 256, 0, stream>>>(wq, wqb, (int)wsz);
        cast_bf16<<<(int)(wsz / 2048), 256, 0, stream>>>(wk, wkb, (int)wsz);
        cast_bf16<<<(int)(wsz / 2048), 256, 0, stream>>>(wv, wvb, (int)wsz);
        cast_bf16<<<(int)(wsz / 2048), 256, 0, stream>>>(wo, wob, (int)wsz);

        dim3 gg(M / 128, D_MODEL / 128);          // (32, 8)
        gemm128_bt<false><<<gg, 256, 0, stream>>>(xb, wqb, Qw, M, D_MODEL, D_MODEL);
        gemm128_bt<false><<<gg, 256, 0, stream>>>(xb, wkb, Kw, M, D_MODEL, D_MODEL);
        gemm128_bt<false><<<gg, 256, 0, stream>>>(xb, wvb, Vw, M, D_MODEL, D_MODEL);
        attn_v2<<<dim3(SEQ / 128, BATCH * NHEAD), 256, 0, stream>>>(Qw, Kw, Vw, Yw);
        gemm128_bt<true><<<gg, 256, 0, stream>>>(Yw, wob, d_out, M, D_MODEL, D_MODEL);
    } else {
        // fallback: r4 GEMMs (register-converted fp32 operands)
        dim3 gg(M / 64, D_MODEL / 64);
        gemm_bt<true, true, false><<<gg, 256, 0, stream>>>(x, wq, Qw, M, D_MODEL, D_MODEL);
        gemm_bt<true, true, false><<<gg, 256, 0, stream>>>(x, wk, Kw, M, D_MODEL, D_MODEL);
        gemm_bt<true, true, false><<<gg, 256, 0, stream>>>(x, wv, Vw, M, D_MODEL, D_MODEL);
        attn_v2<<<dim3(SEQ / 128, BATCH * NHEAD), 256, 0, stream>>>(Qw, Kw, Vw, Yw);
        gemm_bt<false, true, true><<<gg, 256, 0, stream>>>(Yw, wo, d_out, M, D_MODEL, D_MODEL);
    }
}